// Round 10
// baseline (849.132 us; speedup 1.0000x reference)
//
#include <hip/hip_runtime.h>
#include <float.h>
#include <math.h>

#define K_CODES 1024
#define ED 64
#define NTOK 131072
#define EPS_DOT 2e-4f   // proven round-8: ~16% ambiguous, model-calibrated

typedef __attribute__((ext_vector_type(8)))  short short8;   // 8 bf16 (4 VGPRs)
typedef __attribute__((ext_vector_type(16))) float float16;  // MFMA 32x32 acc

// ---------------------------------------------------------------------------
// NUMERICS OF THE EXACT PATH ARE FROZEN (rounds 2-9 passed, 0 argmin flips):
//  - zsq / e_sq: numpy pairwise_sum n=64 (8 accs strided 8, mul+add no fma,
//    combine ((r0+r1)+(r2+r3))+((r4+r5)+(r6+r7))), contract(off).
//  - dot(z,e): single sequential fmaf chain over d=0..63.
//  - d2 = fmaf(-2,dot,zsq) + e_sq.
//  - argmin: smallest d2, smallest index on exact tie (np.argmin).
// Approx path: round-8 scoring EXACTLY (dot only, no esq bias — the round-9
// bias MFMA empirically added 7x more ambiguity than the gap model; reverted).
// V2 >= V1 - EPS_DOT -> token rescued by FULL exact 1024-code scan.
// Round-8/9 lesson: NEVER hold a 64-float array per lane (allocator caps at
// 48 VGPR and spills to scratch; 600+us). Rescue streams z and e from
// global/L1 with ~10 live scalars.
// ---------------------------------------------------------------------------

static __device__ __forceinline__ unsigned short f2bf(float x) {  // RNE
    unsigned u = __float_as_uint(x);
    u += 0x7fffu + ((u >> 16) & 1u);
    return (unsigned short)(u >> 16);
}
static __device__ __forceinline__ float bf2f(unsigned short h) {
    return __uint_as_float(((unsigned)h) << 16);
}

// ---------------------------------------------------------------------------
// prep: codebook frags (layout proven r6-9) + frozen e_sq; zero counts/sse.
// frag[(ct*8 + g)*32 + (k&31)], g = d/8.
// ---------------------------------------------------------------------------
__global__ __launch_bounds__(256) void vq_prep(const float* __restrict__ cb,
                                               float* __restrict__ e_sq,
                                               short8* __restrict__ efH,
                                               short8* __restrict__ efL,
                                               unsigned int* __restrict__ counts,
                                               float* __restrict__ sse,
                                               unsigned int* __restrict__ wcount)
{
#pragma clang fp contract(off)
    const int k = blockIdx.x * 256 + threadIdx.x;   // 0..1023
    const float4* ep = (const float4*)(cb + (size_t)k * ED);
    const int m = k & 31, ct = k >> 5;
    float r[8];
#pragma unroll
    for (int g = 0; g < 8; ++g) {
        float4 a = ep[2 * g], b = ep[2 * g + 1];
        float v[8] = {a.x, a.y, a.z, a.w, b.x, b.y, b.z, b.w};
        short8 hv, lv;
#pragma unroll
        for (int j = 0; j < 8; ++j) {
            unsigned short hb = f2bf(v[j]);
            hv[j] = (short)hb;
            lv[j] = (short)f2bf(v[j] - bf2f(hb));
            const float sq = v[j] * v[j];          // frozen pairwise e_sq
            r[j] = g ? (r[j] + sq) : sq;
        }
        efH[(ct * 8 + g) * 32 + m] = hv;
        efL[(ct * 8 + g) * 32 + m] = lv;
    }
    e_sq[k] = ((r[0] + r[1]) + (r[2] + r[3])) + ((r[4] + r[5]) + (r[6] + r[7]));
    counts[k] = 0u;
    if (k == 0) { *sse = 0.f; *wcount = 0u; }
}

// ---------------------------------------------------------------------------
// fused (round-8 exactly): block = 256 tokens; z->LDS; bf16 hi/lo B-frags in
// regs; MFMA over 32 code-tiles; running (V1,I1,V2); unambiguous -> epilogue,
// ambiguous -> worklist.  LDS ~73.7 KB -> 2 blocks/CU.
// ---------------------------------------------------------------------------
__global__ __launch_bounds__(256, 2) void vq_fused(const float* __restrict__ z_e,
                                                   const float* __restrict__ cb,
                                                   const short8* __restrict__ efH,
                                                   const short8* __restrict__ efL,
                                                   float* __restrict__ out_zq,
                                                   float* __restrict__ out_idx,
                                                   unsigned int* __restrict__ counts,
                                                   float* __restrict__ sse,
                                                   unsigned int* __restrict__ wlist,
                                                   unsigned int* __restrict__ wcount)
{
#pragma clang fp contract(off)
    __shared__ __align__(16) float zs[256 * 68];   // [token][68]
    __shared__ unsigned int hist[K_CODES];
    __shared__ float wsum[4];

    const int tid = threadIdx.x;
    const int lane = tid & 63, wv = tid >> 6;
    const int ml = lane & 31, h = lane >> 5;
    const int t0 = blockIdx.x * 256;
    const int t  = t0 + tid;                       // this thread's token

    for (int i = tid; i < K_CODES; i += 256) hist[i] = 0u;

    // ---- stage z rows (thread <-> token) ----
    {
        const float4* zp = (const float4*)(z_e + (size_t)t * ED);
#pragma unroll
        for (int j = 0; j < 16; ++j)
            *(float4*)&zs[tid * 68 + 4 * j] = zp[j];
    }
    __syncthreads();

    // ---- convert B-frags (regs): lane (ml,h) -> token wv*64+X*32+ml ----
    short8 zh[2][4], zl[2][4];
#pragma unroll
    for (int X = 0; X < 2; ++X) {
        const int tok = wv * 64 + X * 32 + ml;
#pragma unroll
        for (int q = 0; q < 4; ++q) {
            const int g = q * 2 + h;
            const float* p = &zs[tok * 68 + g * 8];
            float4 a = *(const float4*)p, b = *(const float4*)(p + 4);
            float v[8] = {a.x, a.y, a.z, a.w, b.x, b.y, b.z, b.w};
            short8 hv, lv;
#pragma unroll
            for (int j = 0; j < 8; ++j) {
                unsigned short hb = f2bf(v[j]);
                hv[j] = (short)hb;
                lv[j] = (short)f2bf(v[j] - bf2f(hb));
            }
            zh[X][q] = hv;
            zl[X][q] = lv;
        }
    }

    // ---- MFMA over 32 code-tiles with running 2-max trackers ----
    float V1[2] = {-FLT_MAX, -FLT_MAX}, V2[2] = {-FLT_MAX, -FLT_MAX};
    int   I1[2] = {0, 0};

    short8 ecur[8], enxt[8];                       // [0..3]=H, [4..7]=L
#pragma unroll
    for (int q = 0; q < 4; ++q) {
        const int idx = (q * 2 + h) * 32 + ml;
        ecur[q] = efH[idx]; ecur[4 + q] = efL[idx];
    }

    for (int ct = 0; ct < 32; ++ct) {
        if (ct < 31) {
#pragma unroll
            for (int q = 0; q < 4; ++q) {
                const int idx = ((ct + 1) * 8 + q * 2 + h) * 32 + ml;
                enxt[q] = efH[idx]; enxt[4 + q] = efL[idx];
            }
        }
        float16 acc0 = {}, acc1 = {};
#pragma unroll
        for (int q = 0; q < 4; ++q) {              // proven order: hh, hl, lh
            acc0 = __builtin_amdgcn_mfma_f32_32x32x16_bf16(ecur[q],     zh[0][q], acc0, 0, 0, 0);
            acc1 = __builtin_amdgcn_mfma_f32_32x32x16_bf16(ecur[q],     zh[1][q], acc1, 0, 0, 0);
            acc0 = __builtin_amdgcn_mfma_f32_32x32x16_bf16(ecur[q],     zl[0][q], acc0, 0, 0, 0);
            acc1 = __builtin_amdgcn_mfma_f32_32x32x16_bf16(ecur[q],     zl[1][q], acc1, 0, 0, 0);
            acc0 = __builtin_amdgcn_mfma_f32_32x32x16_bf16(ecur[4 + q], zh[0][q], acc0, 0, 0, 0);
            acc1 = __builtin_amdgcn_mfma_f32_32x32x16_bf16(ecur[4 + q], zh[1][q], acc1, 0, 0, 0);
        }
#pragma unroll
        for (int X = 0; X < 2; ++X) {
            const float16 acc = X ? acc1 : acc0;
            float v1 = -FLT_MAX, v2 = -FLT_MAX;
            int i1 = 0;
#pragma unroll
            for (int rg = 0; rg < 16; ++rg) {
                const float v = acc[rg];
                const int mrow = (rg & 3) + 8 * (rg >> 2) + 4 * h;  // C/D row
                if (v > v1) { v2 = v1; v1 = v; i1 = mrow; }
                else v2 = fmaxf(v2, v);
            }
            const float o1 = __shfl_xor(v1, 32);
            const float o2 = __shfl_xor(v2, 32);
            const int   oi = __shfl_xor(i1, 32);
            const float lo = fminf(v1, o1);
            if (o1 > v1) { v1 = o1; i1 = oi; }
            v2 = fmaxf(lo, fmaxf(v2, o2));         // exact tile 2nd-largest
            if (v1 > V1[X]) { V2[X] = fmaxf(V1[X], v2); V1[X] = v1; I1[X] = ct * 32 + i1; }
            else            { V2[X] = fmaxf(V2[X], v1); }
        }
#pragma unroll
        for (int i = 0; i < 8; ++i) ecur[i] = enxt[i];
    }

    // thread tid's token: local = wv*64 + h*32 + ml -> tile X = h, col = ml
    const float v1f = V1[h], v2f = V2[h];
    const int   i1f = I1[h];
    const bool amb = (v2f >= v1f - EPS_DOT);

    float lsse = 0.f;
    if (!amb) {
        const int bi = i1f;                        // provably exact argmin
        atomicAdd(&hist[bi], 1u);
        out_idx[t] = (float)bi;
        const float4* eq = (const float4*)(cb + (size_t)bi * ED);
        float4* oz = (float4*)(out_zq + (size_t)t * ED);
#pragma unroll
        for (int i = 0; i < 16; ++i) {
            float4 q = eq[i];
            oz[i] = q;
            const float* zrow = &zs[tid * 68 + 4 * i];
            float dx = q.x - zrow[0]; lsse = fmaf(dx, dx, lsse);
            float dy = q.y - zrow[1]; lsse = fmaf(dy, dy, lsse);
            float dz = q.z - zrow[2]; lsse = fmaf(dz, dz, lsse);
            float dw = q.w - zrow[3]; lsse = fmaf(dw, dw, lsse);
        }
    } else {
        const unsigned pos = atomicAdd(wcount, 1u);
        wlist[pos] = (unsigned)t;
    }

    // block SSE reduce (unambiguous tokens only)
#pragma unroll
    for (int off = 32; off > 0; off >>= 1)
        lsse += __shfl_down(lsse, off, 64);
    if (lane == 0) wsum[wv] = lsse;
    __syncthreads();
    if (tid == 0)
        atomicAdd(sse, (wsum[0] + wsum[1]) + (wsum[2] + wsum[3]));
    for (int i = tid; i < K_CODES; i += 256) {
        const unsigned int c = hist[i];
        if (c) atomicAdd(&counts[i], c);
    }
}

// ---------------------------------------------------------------------------
// rescue: one wave per ambiguous token; FULL exact 1024-code scan, frozen
// chain. NO register arrays: z row is re-read float4-wise from global at
// wave-uniform addresses (L1-broadcast, row L1-resident), e rows streamed.
// Live state ~10 scalars -> spill-proof regardless of allocator heuristic.
// ---------------------------------------------------------------------------
__global__ __launch_bounds__(256) void vq_rescue(const float* __restrict__ z_e,
                                                 const float* __restrict__ cb,
                                                 const float* __restrict__ e_sq,
                                                 const unsigned int* __restrict__ wlist,
                                                 const unsigned int* __restrict__ wcount,
                                                 float* __restrict__ out_zq,
                                                 float* __restrict__ out_idx,
                                                 unsigned int* __restrict__ counts,
                                                 float* __restrict__ sse)
{
#pragma clang fp contract(off)
    const int tid = threadIdx.x, lane = tid & 63, wv = tid >> 6;
    const int wave = blockIdx.x * 4 + wv, nw = gridDim.x * 4;
    const int n = (int)*wcount;

    for (int it = wave; it < n; it += nw) {
        const int t = (int)wlist[it];
        const float4* zp = (const float4*)(z_e + (size_t)t * ED);

        // frozen pairwise zsq, streamed (r[8] only; no z array)
        float r[8];
#pragma unroll
        for (int g = 0; g < 8; ++g) {
            const float4 a = zp[2 * g], b = zp[2 * g + 1];
            const float v0 = a.x, v1 = a.y, v2 = a.z, v3 = a.w;
            const float v4 = b.x, v5 = b.y, v6 = b.z, v7 = b.w;
            if (g == 0) {
                r[0] = v0 * v0; r[1] = v1 * v1; r[2] = v2 * v2; r[3] = v3 * v3;
                r[4] = v4 * v4; r[5] = v5 * v5; r[6] = v6 * v6; r[7] = v7 * v7;
            } else {
                r[0] = r[0] + v0 * v0; r[1] = r[1] + v1 * v1;
                r[2] = r[2] + v2 * v2; r[3] = r[3] + v3 * v3;
                r[4] = r[4] + v4 * v4; r[5] = r[5] + v5 * v5;
                r[6] = r[6] + v6 * v6; r[7] = r[7] + v7 * v7;
            }
        }
        const float zsq =
            ((r[0] + r[1]) + (r[2] + r[3])) + ((r[4] + r[5]) + (r[6] + r[7]));

        float best = FLT_MAX;
        int bi = K_CODES;
        for (int cc = 0; cc < 16; ++cc) {
            const int c = cc * 64 + lane;
            const float4* e4 = (const float4*)(cb + (size_t)c * ED);
            float a = 0.f;
#pragma unroll 4
            for (int j = 0; j < 16; ++j) {         // streamed z + e, no arrays
                const float4 zv = zp[j];           // wave-uniform -> L1 bcast
                const float4 ev = e4[j];
                a = fmaf(zv.x, ev.x, a);           // frozen sequential chain
                a = fmaf(zv.y, ev.y, a);
                a = fmaf(zv.z, ev.z, a);
                a = fmaf(zv.w, ev.w, a);
            }
            const float d2 = fmaf(-2.f, a, zsq) + e_sq[c];
            if (d2 < best || (d2 == best && c < bi)) { best = d2; bi = c; }
        }
        // wave lexicographic (value, index) min-reduce = np.argmin
#pragma unroll
        for (int off = 32; off > 0; off >>= 1) {
            const float ov = __shfl_xor(best, off);
            const int   oi = __shfl_xor(bi, off);
            if (ov < best || (ov == best && oi < bi)) { best = ov; bi = oi; }
        }
        // epilogue: lane <-> d, coalesced
        const float qd = cb[(size_t)bi * ED + lane];
        const float zd = z_e[(size_t)t * ED + lane];
        out_zq[(size_t)t * ED + lane] = qd;
        float s = (qd - zd) * (qd - zd);
#pragma unroll
        for (int off = 32; off > 0; off >>= 1)
            s += __shfl_down(s, off, 64);
        if (lane == 0) {
            atomicAdd(sse, s);
            atomicAdd(&counts[bi], 1u);
            out_idx[t] = (float)bi;
        }
    }
}

// ---------------------------------------------------------------------------
// final: entropy / losses scalars
// ---------------------------------------------------------------------------
__global__ __launch_bounds__(1024) void vq_final(const unsigned int* __restrict__ counts,
                                                 const float* __restrict__ sse,
                                                 float* __restrict__ out_sc)
{
    __shared__ float red[1024];
    const int i = threadIdx.x;
    const float c = (float)counts[i];
    const float p = c / (float)NTOK + 1e-10f;
    red[i] = p * logf(p);
    __syncthreads();
    for (int s = 512; s > 0; s >>= 1) {
        if (i < s) red[i] += red[i + s];
        __syncthreads();
    }
    if (i == 0) {
        const float entropy = -red[0];
        const float cbl = (*sse) / ((float)NTOK * (float)ED);
        out_sc[0] = cbl;                                   // codebook_loss
        out_sc[1] = 0.25f * cbl;                           // commitment_loss
        out_sc[2] = -0.1f * (entropy / 6.93147180559945f); // entropy_loss
        out_sc[3] = expf(entropy);                         // perplexity
    }
}

// ---------------------------------------------------------------------------
extern "C" void kernel_launch(void* const* d_in, const int* in_sizes, int n_in,
                              void* d_out, int out_size, void* d_ws, size_t ws_size,
                              hipStream_t stream)
{
    const float* z_e = (const float*)d_in[0];
    const float* cb  = (const float*)d_in[1];

    float* out   = (float*)d_out;
    float* o_zq  = out;                              // [131072,64]
    float* o_idx = out + (size_t)NTOK * ED;          // [131072] (as float)
    float* o_sc  = o_idx + NTOK;                     // 4 scalars

    char* ws = (char*)d_ws;
    float*        e_sq   = (float*)(ws);                     // 4 KB
    unsigned int* counts = (unsigned int*)(ws + 4096);       // 4 KB
    float*        sse    = (float*)(ws + 8192);              // 4 B
    unsigned int* wcount = (unsigned int*)(ws + 8196);       // 4 B
    unsigned int* wlist  = (unsigned int*)(ws + 12288);      // 512 KB
    short8*       efH    = (short8*)(ws + 540672);           // 128 KB
    short8*       efL    = (short8*)(ws + 671744);           // 128 KB

    vq_prep  <<<4, 256, 0, stream>>>(cb, e_sq, efH, efL, counts, sse, wcount);
    vq_fused <<<NTOK / 256, 256, 0, stream>>>(z_e, cb, efH, efL,
                                              o_zq, o_idx, counts, sse,
                                              wlist, wcount);
    vq_rescue<<<1024, 256, 0, stream>>>(z_e, cb, e_sq, wlist, wcount,
                                        o_zq, o_idx, counts, sse);
    vq_final <<<1, 1024, 0, stream>>>(counts, sse, o_sc);
}

// Round 11
// 256.270 us; speedup vs baseline: 3.3134x; 3.3134x over previous
//
#include <hip/hip_runtime.h>
#include <float.h>
#include <math.h>

#define K_CODES 1024
#define ED 64
#define NTOK 131072
#define EPS_DOT 4e-5f   // exact esq bias in score -> residual err ~1e-5, 4x margin

typedef __attribute__((ext_vector_type(8)))  short short8;   // 8 bf16 (4 VGPRs)
typedef __attribute__((ext_vector_type(16))) float float16;  // MFMA 32x32 acc

// ---------------------------------------------------------------------------
// NUMERICS OF THE EXACT PATH ARE FROZEN (rounds 2-10 passed, 0 argmin flips):
//  - zsq / e_sq: numpy pairwise_sum n=64 (8 accs strided 8, mul+add no fma,
//    combine ((r0+r1)+(r2+r3))+((r4+r5)+(r6+r7))), contract(off).
//  - dot(z,e): single sequential fmaf chain over d=0..63.
//  - d2 = fmaf(-2,dot,zsq) + e_sq.
//  - argmin: smallest d2, smallest index on exact tie (np.argmin).
// Approx score = dot - e_sq/2 with e_sq bias applied EXACTLY (fp32) via MFMA
// C-register initialization (NOT a bias MFMA - round 9's failed). Tokens with
// approx top-2 gap > EPS_DOT: I1 is provably the exact argmin. Gap <= EPS but
// 3rd-best out of band: exact argmin is in {I1,I2} -> vq_res2 rescores both
// with the frozen chain (2 chains/token). 3rd-best also in band (~100 tokens):
// vq_resfull full 1024-code frozen scan. All paths bit-identical to reference.
// Round 8/9/10 lessons: no 64-float register arrays anywhere (allocator caps
// at 48 VGPR and spills or serializes); rescue work must be O(candidates).
// ---------------------------------------------------------------------------

static __device__ __forceinline__ unsigned short f2bf(float x) {  // RNE
    unsigned u = __float_as_uint(x);
    u += 0x7fffu + ((u >> 16) & 1u);
    return (unsigned short)(u >> 16);
}
static __device__ __forceinline__ float bf2f(unsigned short h) {
    return __uint_as_float(((unsigned)h) << 16);
}

// ---------------------------------------------------------------------------
// prep: codebook frags (layout proven r6-10) + frozen e_sq; zero counters.
// frag[(ct*8 + g)*32 + (k&31)], g = d/8.
// ---------------------------------------------------------------------------
__global__ __launch_bounds__(256) void vq_prep(const float* __restrict__ cb,
                                               float* __restrict__ e_sq,
                                               short8* __restrict__ efH,
                                               short8* __restrict__ efL,
                                               unsigned int* __restrict__ counts,
                                               float* __restrict__ sse,
                                               unsigned int* __restrict__ wc2,
                                               unsigned int* __restrict__ wcF)
{
#pragma clang fp contract(off)
    const int k = blockIdx.x * 256 + threadIdx.x;   // 0..1023
    const float4* ep = (const float4*)(cb + (size_t)k * ED);
    const int m = k & 31, ct = k >> 5;
    float r[8];
#pragma unroll
    for (int g = 0; g < 8; ++g) {
        float4 a = ep[2 * g], b = ep[2 * g + 1];
        float v[8] = {a.x, a.y, a.z, a.w, b.x, b.y, b.z, b.w};
        short8 hv, lv;
#pragma unroll
        for (int j = 0; j < 8; ++j) {
            unsigned short hb = f2bf(v[j]);
            hv[j] = (short)hb;
            lv[j] = (short)f2bf(v[j] - bf2f(hb));
            const float sq = v[j] * v[j];          // frozen pairwise e_sq
            r[j] = g ? (r[j] + sq) : sq;
        }
        efH[(ct * 8 + g) * 32 + m] = hv;
        efL[(ct * 8 + g) * 32 + m] = lv;
    }
    e_sq[k] = ((r[0] + r[1]) + (r[2] + r[3])) + ((r[4] + r[5]) + (r[6] + r[7]));
    counts[k] = 0u;
    if (k == 0) { *sse = 0.f; *wc2 = 0u; *wcF = 0u; }
}

// ---------------------------------------------------------------------------
// fused: block = 256 tokens; z->LDS; bf16 hi/lo B-frags in regs; MFMA over 32
// code-tiles with acc initialized to exact -e_sq/2 (LDS-staged in C/D layout);
// running top-3 values + top-2 indices per token. Unambiguous -> epilogue;
// 2-candidate -> wl2; else -> wlF.  LDS 77.9 KB -> 2 blocks/CU.
// ---------------------------------------------------------------------------
__global__ __launch_bounds__(256, 2) void vq_fused(const float* __restrict__ z_e,
                                                   const float* __restrict__ cb,
                                                   const float* __restrict__ e_sq,
                                                   const short8* __restrict__ efH,
                                                   const short8* __restrict__ efL,
                                                   float* __restrict__ out_zq,
                                                   float* __restrict__ out_idx,
                                                   unsigned int* __restrict__ counts,
                                                   float* __restrict__ sse,
                                                   unsigned int* __restrict__ wl2_tok,
                                                   unsigned int* __restrict__ wl2_idx,
                                                   unsigned int* __restrict__ wc2,
                                                   unsigned int* __restrict__ wlF,
                                                   unsigned int* __restrict__ wcF)
{
#pragma clang fp contract(off)
    __shared__ __align__(16) float zs[256 * 68];       // [token][68]
    __shared__ __align__(16) float bias_l[K_CODES];    // [ct*32 + h*16 + rg]
    __shared__ unsigned int hist[K_CODES];
    __shared__ float wsum[4];

    const int tid = threadIdx.x;
    const int lane = tid & 63, wv = tid >> 6;
    const int ml = lane & 31, h = lane >> 5;
    const int t0 = blockIdx.x * 256;
    const int t  = t0 + tid;                       // this thread's token

    for (int i = tid; i < K_CODES; i += 256) {
        hist[i] = 0u;
        // bias in C/D layout: slot (ct, r5=h*16+rg) -> -e_sq[ct*32+mrow]/2
        const int ct = i >> 5, r5 = i & 31;
        const int hh = r5 >> 4, rg = r5 & 15;
        const int mrow = (rg & 3) + 8 * (rg >> 2) + 4 * hh;
        bias_l[i] = -0.5f * e_sq[ct * 32 + mrow];
    }

    // ---- stage z rows (thread <-> token) ----
    {
        const float4* zp = (const float4*)(z_e + (size_t)t * ED);
#pragma unroll
        for (int j = 0; j < 16; ++j)
            *(float4*)&zs[tid * 68 + 4 * j] = zp[j];
    }
    __syncthreads();

    // ---- convert B-frags (regs): lane (ml,h) -> token wv*64+X*32+ml ----
    short8 zh[2][4], zl[2][4];
#pragma unroll
    for (int X = 0; X < 2; ++X) {
        const int tok = wv * 64 + X * 32 + ml;
#pragma unroll
        for (int q = 0; q < 4; ++q) {
            const int g = q * 2 + h;
            const float* p = &zs[tok * 68 + g * 8];
            float4 a = *(const float4*)p, b = *(const float4*)(p + 4);
            float v[8] = {a.x, a.y, a.z, a.w, b.x, b.y, b.z, b.w};
            short8 hv, lv;
#pragma unroll
            for (int j = 0; j < 8; ++j) {
                unsigned short hb = f2bf(v[j]);
                hv[j] = (short)hb;
                lv[j] = (short)f2bf(v[j] - bf2f(hb));
            }
            zh[X][q] = hv;
            zl[X][q] = lv;
        }
    }

    // ---- running trackers per token-tile X: top-3 values, top-2 indices ----
    float V1[2] = {-FLT_MAX, -FLT_MAX}, V2[2] = {-FLT_MAX, -FLT_MAX},
          V3[2] = {-FLT_MAX, -FLT_MAX};
    int   I1[2] = {0, 0}, I2[2] = {0, 0};

    short8 ecur[8], enxt[8];                       // [0..3]=H, [4..7]=L
#pragma unroll
    for (int q = 0; q < 4; ++q) {
        const int idx = (q * 2 + h) * 32 + ml;
        ecur[q] = efH[idx]; ecur[4 + q] = efL[idx];
    }

    for (int ct = 0; ct < 32; ++ct) {
        if (ct < 31) {
#pragma unroll
            for (int q = 0; q < 4; ++q) {
                const int idx = ((ct + 1) * 8 + q * 2 + h) * 32 + ml;
                enxt[q] = efH[idx]; enxt[4 + q] = efL[idx];
            }
        }
        // acc init = exact -e_sq/2 (broadcast LDS reads, h-dependent only)
        const float4* bp = (const float4*)&bias_l[ct * 32 + h * 16];
        const float4 b0 = bp[0], b1 = bp[1], b2 = bp[2], b3 = bp[3];
        float16 acc0;
        acc0[0] = b0.x; acc0[1] = b0.y; acc0[2]  = b0.z; acc0[3]  = b0.w;
        acc0[4] = b1.x; acc0[5] = b1.y; acc0[6]  = b1.z; acc0[7]  = b1.w;
        acc0[8] = b2.x; acc0[9] = b2.y; acc0[10] = b2.z; acc0[11] = b2.w;
        acc0[12] = b3.x; acc0[13] = b3.y; acc0[14] = b3.z; acc0[15] = b3.w;
        float16 acc1 = acc0;
#pragma unroll
        for (int q = 0; q < 4; ++q) {              // proven order: hh, hl, lh
            acc0 = __builtin_amdgcn_mfma_f32_32x32x16_bf16(ecur[q],     zh[0][q], acc0, 0, 0, 0);
            acc1 = __builtin_amdgcn_mfma_f32_32x32x16_bf16(ecur[q],     zh[1][q], acc1, 0, 0, 0);
            acc0 = __builtin_amdgcn_mfma_f32_32x32x16_bf16(ecur[q],     zl[0][q], acc0, 0, 0, 0);
            acc1 = __builtin_amdgcn_mfma_f32_32x32x16_bf16(ecur[q],     zl[1][q], acc1, 0, 0, 0);
            acc0 = __builtin_amdgcn_mfma_f32_32x32x16_bf16(ecur[4 + q], zh[0][q], acc0, 0, 0, 0);
            acc1 = __builtin_amdgcn_mfma_f32_32x32x16_bf16(ecur[4 + q], zh[1][q], acc1, 0, 0, 0);
        }
#pragma unroll
        for (int X = 0; X < 2; ++X) {
            const float16 acc = X ? acc1 : acc0;
            // per-lane top-3 values + top-2 global indices over 16 regs
            float v1 = -FLT_MAX, v2 = -FLT_MAX, v3 = -FLT_MAX;
            int i1 = 0, i2 = 0;
#pragma unroll
            for (int rg = 0; rg < 16; ++rg) {
                const float v = acc[rg];
                const int gi = ct * 32 + (rg & 3) + 8 * (rg >> 2) + 4 * h;
                if (v > v1)      { v3 = v2; v2 = v1; i2 = i1; v1 = v; i1 = gi; }
                else if (v > v2) { v3 = v2; v2 = v; i2 = gi; }
                else              v3 = fmaxf(v3, v);
            }
            // h-half merge (shfl_xor 32): top-3 of 6, top-2 indices
            const float o1 = __shfl_xor(v1, 32), o2 = __shfl_xor(v2, 32),
                        o3 = __shfl_xor(v3, 32);
            const int   p1 = __shfl_xor(i1, 32), p2 = __shfl_xor(i2, 32);
            float t1, t2, t3; int j1, j2;
            if (o1 > v1) {
                if (o2 > v1) { t1 = o1; j1 = p1; t2 = o2; j2 = p2; t3 = fmaxf(v1, o3); }
                else         { t1 = o1; j1 = p1; t2 = v1; j2 = i1; t3 = fmaxf(v2, o2); }
            } else {
                if (o1 > v2) { t1 = v1; j1 = i1; t2 = o1; j2 = p1; t3 = fmaxf(v2, o2); }
                else         { t1 = v1; j1 = i1; t2 = v2; j2 = i2; t3 = fmaxf(v3, o1); }
            }
            // merge tile (t1,j1,t2,j2,t3) into running
            if (t1 > V1[X]) {
                if (t2 > V1[X]) {
                    V3[X] = fmaxf(V1[X], t3);
                    V1[X] = t1; I1[X] = j1; V2[X] = t2; I2[X] = j2;
                } else {
                    V3[X] = fmaxf(V2[X], t2);
                    V2[X] = V1[X]; I2[X] = I1[X]; V1[X] = t1; I1[X] = j1;
                }
            } else {
                if (t1 > V2[X]) {
                    V3[X] = fmaxf(V2[X], t2);
                    V2[X] = t1; I2[X] = j1;
                } else {
                    V3[X] = fmaxf(V3[X], t1);
                }
            }
        }
#pragma unroll
        for (int i = 0; i < 8; ++i) ecur[i] = enxt[i];
    }

    // thread tid's token: local = wv*64 + h*32 + ml -> tile X = h
    const float v1f = V1[h], v2f = V2[h], v3f = V3[h];
    const int   i1f = I1[h], i2f = I2[h];
    const bool amb = (v2f >= v1f - EPS_DOT);

    float lsse = 0.f;
    if (!amb) {
        const int bi = i1f;                        // provably exact argmin
        atomicAdd(&hist[bi], 1u);
        out_idx[t] = (float)bi;
        const float4* eq = (const float4*)(cb + (size_t)bi * ED);
        float4* oz = (float4*)(out_zq + (size_t)t * ED);
#pragma unroll
        for (int i = 0; i < 16; ++i) {
            float4 q = eq[i];
            oz[i] = q;
            const float* zrow = &zs[tid * 68 + 4 * i];
            float dx = q.x - zrow[0]; lsse = fmaf(dx, dx, lsse);
            float dy = q.y - zrow[1]; lsse = fmaf(dy, dy, lsse);
            float dz = q.z - zrow[2]; lsse = fmaf(dz, dz, lsse);
            float dw = q.w - zrow[3]; lsse = fmaf(dw, dw, lsse);
        }
    } else if (v3f < v1f - EPS_DOT) {
        // exact argmin is in {I1,I2}: 2-candidate rescore worklist
        const unsigned pos = atomicAdd(wc2, 1u);
        wl2_tok[pos] = (unsigned)t;
        wl2_idx[pos] = (unsigned)i1f | ((unsigned)i2f << 16);
    } else {
        const unsigned pos = atomicAdd(wcF, 1u);   // rare: full scan
        wlF[pos] = (unsigned)t;
    }

    // block SSE reduce (unambiguous tokens only)
#pragma unroll
    for (int off = 32; off > 0; off >>= 1)
        lsse += __shfl_down(lsse, off, 64);
    if (lane == 0) wsum[wv] = lsse;
    __syncthreads();
    if (tid == 0)
        atomicAdd(sse, (wsum[0] + wsum[1]) + (wsum[2] + wsum[3]));
    for (int i = tid; i < K_CODES; i += 256) {
        const unsigned int c = hist[i];
        if (c) atomicAdd(&counts[i], c);
    }
}

// ---------------------------------------------------------------------------
// res2: thread <-> ambiguous token; frozen-chain rescore of the 2 candidates
// (streamed loads, ~10 live scalars, spill-proof) + epilogue.
// ---------------------------------------------------------------------------
__global__ __launch_bounds__(256) void vq_res2(const float* __restrict__ z_e,
                                               const float* __restrict__ cb,
                                               const float* __restrict__ e_sq,
                                               const unsigned int* __restrict__ wl2_tok,
                                               const unsigned int* __restrict__ wl2_idx,
                                               const unsigned int* __restrict__ wc2,
                                               float* __restrict__ out_zq,
                                               float* __restrict__ out_idx,
                                               unsigned int* __restrict__ counts,
                                               float* __restrict__ sse)
{
#pragma clang fp contract(off)
    const int gtid = blockIdx.x * 256 + threadIdx.x;
    const int stride = gridDim.x * 256;
    const int n = (int)*wc2;
    float lsse = 0.f;

    for (int i = gtid; i < n; i += stride) {
        const int t = (int)wl2_tok[i];
        const unsigned pk = wl2_idx[i];
        const int c1 = (int)(pk & 0xFFFFu), c2 = (int)(pk >> 16);
        const float4* zp = (const float4*)(z_e + (size_t)t * ED);

        // frozen pairwise zsq, streamed
        float r[8];
#pragma unroll
        for (int g = 0; g < 8; ++g) {
            const float4 a = zp[2 * g], b = zp[2 * g + 1];
            if (g == 0) {
                r[0] = a.x * a.x; r[1] = a.y * a.y; r[2] = a.z * a.z; r[3] = a.w * a.w;
                r[4] = b.x * b.x; r[5] = b.y * b.y; r[6] = b.z * b.z; r[7] = b.w * b.w;
            } else {
                r[0] = r[0] + a.x * a.x; r[1] = r[1] + a.y * a.y;
                r[2] = r[2] + a.z * a.z; r[3] = r[3] + a.w * a.w;
                r[4] = r[4] + b.x * b.x; r[5] = r[5] + b.y * b.y;
                r[6] = r[6] + b.z * b.z; r[7] = r[7] + b.w * b.w;
            }
        }
        const float zsq =
            ((r[0] + r[1]) + (r[2] + r[3])) + ((r[4] + r[5]) + (r[6] + r[7]));

        float d2v[2];
        const int cc[2] = {c1, c2};
#pragma unroll
        for (int s = 0; s < 2; ++s) {
            const float4* e4 = (const float4*)(cb + (size_t)cc[s] * ED);
            float a = 0.f;
#pragma unroll 4
            for (int j = 0; j < 16; ++j) {         // streamed, frozen chain
                const float4 zv = zp[j];
                const float4 ev = e4[j];
                a = fmaf(zv.x, ev.x, a);
                a = fmaf(zv.y, ev.y, a);
                a = fmaf(zv.z, ev.z, a);
                a = fmaf(zv.w, ev.w, a);
            }
            d2v[s] = fmaf(-2.f, a, zsq) + e_sq[cc[s]];
        }
        int bi = c1; float bd = d2v[0];
        if (d2v[1] < bd || (d2v[1] == bd && c2 < c1)) { bi = c2; bd = d2v[1]; }

        out_idx[t] = (float)bi;
        atomicAdd(&counts[bi], 1u);
        const float4* eq = (const float4*)(cb + (size_t)bi * ED);
        float4* oz = (float4*)(out_zq + (size_t)t * ED);
#pragma unroll
        for (int j = 0; j < 16; ++j) {
            const float4 q = eq[j];
            const float4 zv = zp[j];
            oz[j] = q;
            float dx = q.x - zv.x; lsse = fmaf(dx, dx, lsse);
            float dy = q.y - zv.y; lsse = fmaf(dy, dy, lsse);
            float dz = q.z - zv.z; lsse = fmaf(dz, dz, lsse);
            float dw = q.w - zv.w; lsse = fmaf(dw, dw, lsse);
        }
    }
    // wave reduce, one atomic per wave
#pragma unroll
    for (int off = 32; off > 0; off >>= 1)
        lsse += __shfl_down(lsse, off, 64);
    if ((threadIdx.x & 63) == 0 && lsse != 0.f) atomicAdd(sse, lsse);
}

// ---------------------------------------------------------------------------
// resfull: one wave per token; FULL exact 1024-code frozen scan (proven r10
// structure). Expected ~100 tokens -> cost negligible.
// ---------------------------------------------------------------------------
__global__ __launch_bounds__(256) void vq_resfull(const float* __restrict__ z_e,
                                                  const float* __restrict__ cb,
                                                  const float* __restrict__ e_sq,
                                                  const unsigned int* __restrict__ wlF,
                                                  const unsigned int* __restrict__ wcF,
                                                  float* __restrict__ out_zq,
                                                  float* __restrict__ out_idx,
                                                  unsigned int* __restrict__ counts,
                                                  float* __restrict__ sse)
{
#pragma clang fp contract(off)
    const int tid = threadIdx.x, lane = tid & 63, wv = tid >> 6;
    const int wave = blockIdx.x * 4 + wv, nw = gridDim.x * 4;
    const int n = (int)*wcF;

    for (int it = wave; it < n; it += nw) {
        const int t = (int)wlF[it];
        const float4* zp = (const float4*)(z_e + (size_t)t * ED);

        float r[8];
#pragma unroll
        for (int g = 0; g < 8; ++g) {
            const float4 a = zp[2 * g], b = zp[2 * g + 1];
            if (g == 0) {
                r[0] = a.x * a.x; r[1] = a.y * a.y; r[2] = a.z * a.z; r[3] = a.w * a.w;
                r[4] = b.x * b.x; r[5] = b.y * b.y; r[6] = b.z * b.z; r[7] = b.w * b.w;
            } else {
                r[0] = r[0] + a.x * a.x; r[1] = r[1] + a.y * a.y;
                r[2] = r[2] + a.z * a.z; r[3] = r[3] + a.w * a.w;
                r[4] = r[4] + b.x * b.x; r[5] = r[5] + b.y * b.y;
                r[6] = r[6] + b.z * b.z; r[7] = r[7] + b.w * b.w;
            }
        }
        const float zsq =
            ((r[0] + r[1]) + (r[2] + r[3])) + ((r[4] + r[5]) + (r[6] + r[7]));

        float best = FLT_MAX;
        int bi = K_CODES;
        for (int cc = 0; cc < 16; ++cc) {
            const int c = cc * 64 + lane;
            const float4* e4 = (const float4*)(cb + (size_t)c * ED);
            float a = 0.f;
#pragma unroll 4
            for (int j = 0; j < 16; ++j) {
                const float4 zv = zp[j];
                const float4 ev = e4[j];
                a = fmaf(zv.x, ev.x, a);
                a = fmaf(zv.y, ev.y, a);
                a = fmaf(zv.z, ev.z, a);
                a = fmaf(zv.w, ev.w, a);
            }
            const float d2 = fmaf(-2.f, a, zsq) + e_sq[c];
            if (d2 < best || (d2 == best && c < bi)) { best = d2; bi = c; }
        }
#pragma unroll
        for (int off = 32; off > 0; off >>= 1) {
            const float ov = __shfl_xor(best, off);
            const int   oi = __shfl_xor(bi, off);
            if (ov < best || (ov == best && oi < bi)) { best = ov; bi = oi; }
        }
        const float qd = cb[(size_t)bi * ED + lane];
        const float zd = z_e[(size_t)t * ED + lane];
        out_zq[(size_t)t * ED + lane] = qd;
        float s = (qd - zd) * (qd - zd);
#pragma unroll
        for (int off = 32; off > 0; off >>= 1)
            s += __shfl_down(s, off, 64);
        if (lane == 0) {
            atomicAdd(sse, s);
            atomicAdd(&counts[bi], 1u);
            out_idx[t] = (float)bi;
        }
    }
}

// ---------------------------------------------------------------------------
// final: entropy / losses scalars
// ---------------------------------------------------------------------------
__global__ __launch_bounds__(1024) void vq_final(const unsigned int* __restrict__ counts,
                                                 const float* __restrict__ sse,
                                                 float* __restrict__ out_sc)
{
    __shared__ float red[1024];
    const int i = threadIdx.x;
    const float c = (float)counts[i];
    const float p = c / (float)NTOK + 1e-10f;
    red[i] = p * logf(p);
    __syncthreads();
    for (int s = 512; s > 0; s >>= 1) {
        if (i < s) red[i] += red[i + s];
        __syncthreads();
    }
    if (i == 0) {
        const float entropy = -red[0];
        const float cbl = (*sse) / ((float)NTOK * (float)ED);
        out_sc[0] = cbl;                                   // codebook_loss
        out_sc[1] = 0.25f * cbl;                           // commitment_loss
        out_sc[2] = -0.1f * (entropy / 6.93147180559945f); // entropy_loss
        out_sc[3] = expf(entropy);                         // perplexity
    }
}

// ---------------------------------------------------------------------------
extern "C" void kernel_launch(void* const* d_in, const int* in_sizes, int n_in,
                              void* d_out, int out_size, void* d_ws, size_t ws_size,
                              hipStream_t stream)
{
    const float* z_e = (const float*)d_in[0];
    const float* cb  = (const float*)d_in[1];

    float* out   = (float*)d_out;
    float* o_zq  = out;                              // [131072,64]
    float* o_idx = out + (size_t)NTOK * ED;          // [131072] (as float)
    float* o_sc  = o_idx + NTOK;                     // 4 scalars

    char* ws = (char*)d_ws;
    float*        e_sq    = (float*)(ws);                    // 4 KB
    unsigned int* counts  = (unsigned int*)(ws + 4096);      // 4 KB
    float*        sse     = (float*)(ws + 8192);             // 4 B
    unsigned int* wc2     = (unsigned int*)(ws + 8196);      // 4 B
    unsigned int* wcF     = (unsigned int*)(ws + 8200);      // 4 B
    unsigned int* wl2_tok = (unsigned int*)(ws + 12288);     // 512 KB
    unsigned int* wl2_idx = (unsigned int*)(ws + 536576);    // 512 KB
    unsigned int* wlF     = (unsigned int*)(ws + 1060864);   // 512 KB
    short8*       efH     = (short8*)(ws + 1585152);         // 128 KB
    short8*       efL     = (short8*)(ws + 1716224);         // 128 KB

    vq_prep   <<<4, 256, 0, stream>>>(cb, e_sq, efH, efL, counts, sse, wc2, wcF);
    vq_fused  <<<NTOK / 256, 256, 0, stream>>>(z_e, cb, e_sq, efH, efL,
                                               o_zq, o_idx, counts, sse,
                                               wl2_tok, wl2_idx, wc2, wlF, wcF);
    vq_res2   <<<64, 256, 0, stream>>>(z_e, cb, e_sq, wl2_tok, wl2_idx, wc2,
                                       o_zq, o_idx, counts, sse);
    vq_resfull<<<256, 256, 0, stream>>>(z_e, cb, e_sq, wlF, wcF,
                                        o_zq, o_idx, counts, sse);
    vq_final  <<<1, 1024, 0, stream>>>(counts, sse, o_sc);
}